// Round 4
// baseline (1265.029 us; speedup 1.0000x reference)
//
#include <hip/hip_runtime.h>
#include <math.h>

#define B_   32
#define C_   1536
#define N_   1024
#define HID_ 512
#define L_   128
#define M_   64
#define G_   256

typedef unsigned short u16;
typedef unsigned int   u32;
typedef short bf16x8 __attribute__((ext_vector_type(8)));
typedef float f32x4  __attribute__((ext_vector_type(4)));

__device__ __forceinline__ u16 f2bf(float v) {
    u32 u = __float_as_uint(v);
    return (u16)((u + 0x7fffu + ((u >> 16) & 1u)) >> 16);   // RNE
}
__device__ __forceinline__ float bf2f(u16 b) { return __uint_as_float(((u32)b) << 16); }
__device__ __forceinline__ float bflo(u32 u) { return __uint_as_float(u << 16); }
__device__ __forceinline__ float bfhi(u32 u) { return __uint_as_float(u & 0xffff0000u); }

__device__ __forceinline__ void gload16(const u16* g, u16* l) {
    __builtin_amdgcn_global_load_lds(
        (const __attribute__((address_space(1))) void*)g,
        (__attribute__((address_space(3))) void*)l, 16, 0, 0);
}

// ---------------------------------------------------------------- prep: split f32 -> bf16 hi/lo
__global__ __launch_bounds__(256)
void k_split(const float* __restrict__ src, u16* __restrict__ h, u16* __restrict__ l, int n4)
{
    const int i = blockIdx.x * 256 + threadIdx.x;
    if (i >= n4) return;
    const float4 v = ((const float4*)src)[i];
    const u16 h0 = f2bf(v.x), h1 = f2bf(v.y), h2 = f2bf(v.z), h3 = f2bf(v.w);
    *(uint2*)&h[(size_t)i * 4] =
        make_uint2((u32)h0 | ((u32)h1 << 16), (u32)h2 | ((u32)h3 << 16));
    const u16 l0 = f2bf(v.x - bf2f(h0)), l1 = f2bf(v.y - bf2f(h1));
    const u16 l2 = f2bf(v.z - bf2f(h2)), l3 = f2bf(v.w - bf2f(h3));
    *(uint2*)&l[(size_t)i * 4] =
        make_uint2((u32)l0 | ((u32)l1 << 16), (u32)l2 | ((u32)l3 << 16));
}

// ---------------------------------------------------------------- prep: transpose x [b][C][N] -> xT [b][N][C] bf16 hi(/lo)
template<int THIRD>
__global__ __launch_bounds__(256)
void k_prep_xt(const float* __restrict__ x, u16* __restrict__ xTh, u16* __restrict__ xTl)
{
    __shared__ float T[64][65];
    const int tid = threadIdx.x;
    const int j0 = blockIdx.x * 64, c0 = blockIdx.y * 64, b = blockIdx.z;
    const int row = tid >> 2, cq = (tid & 3) * 16;
    const float* src = x + ((size_t)b * C_ + c0 + row) * N_ + j0 + cq;
    *(float4*)&T[row][cq + 0]  = *(const float4*)(src + 0);
    *(float4*)&T[row][cq + 4]  = *(const float4*)(src + 4);
    *(float4*)&T[row][cq + 8]  = *(const float4*)(src + 8);
    *(float4*)&T[row][cq + 12] = *(const float4*)(src + 12);
    __syncthreads();
    u32 ph[8], pl[8];
    #pragma unroll
    for (int i2 = 0; i2 < 8; ++i2) {
        const float f0 = T[cq + i2 * 2][row], f1 = T[cq + i2 * 2 + 1][row];
        const u16 h0 = f2bf(f0), h1 = f2bf(f1);
        ph[i2] = (u32)h0 | ((u32)h1 << 16);
        if (THIRD) {
            const u16 l0 = f2bf(f0 - bf2f(h0)), l1 = f2bf(f1 - bf2f(h1));
            pl[i2] = (u32)l0 | ((u32)l1 << 16);
        }
    }
    u16* dh = xTh + ((size_t)b * N_ + j0 + row) * C_ + c0 + cq;
    *(uint4*)(dh + 0) = make_uint4(ph[0], ph[1], ph[2], ph[3]);
    *(uint4*)(dh + 8) = make_uint4(ph[4], ph[5], ph[6], ph[7]);
    if (THIRD) {
        u16* dl = xTl + ((size_t)b * N_ + j0 + row) * C_ + c0 + cq;
        *(uint4*)(dl + 0) = make_uint4(pl[0], pl[1], pl[2], pl[3]);
        *(uint4*)(dl + 8) = make_uint4(pl[4], pl[5], pl[6], pl[7]);
    }
}

// ---------------------------------------------------------------- K1: conv1, 256x256 tile, BK=32, 8-phase-style pipeline
// H1T[b][j][o] (bf16 hi+lo) = relu(W[o]·x[b,:,j] + bias)
template<int THIRD>
__global__ __launch_bounds__(512, 2)
void k_conv1_v3(const u16* __restrict__ A1h, const u16* __restrict__ A1l,
                const u16* __restrict__ xTh, const u16* __restrict__ xTl,
                const float* __restrict__ bc1, const float* __restrict__ bs1,
                u16* __restrict__ H1Th, u16* __restrict__ H1Tl)
{
    // 2 staging buffers x 32768 u16: {Ah:0 Al:8192 Bh:16384 Bl:24576}, each 256rows x 4 k-chunks
    __shared__ u16 sm[65536];   // 128 KiB; epilogue reuses first 68 KB
    const int tid = threadIdx.x;
    const int j0 = blockIdx.x * 256, o0 = blockIdx.y * 256, b = blockIdx.z;

    const int r256 = tid & 255, qb = tid >> 8;   // staging slot: row, k-chunk(0/1; +2 for slot1)
    const size_t aG = (size_t)(o0 + r256) * C_ + qb * 8;
    const size_t bG = ((size_t)b * N_ + j0 + r256) * C_ + qb * 8;
    const int s0 = tid * 8;                      // slot0 LDS off (u16); slot1 = s0+4096

    const int w = tid >> 6, lane = tid & 63;
    const int wr = w >> 2, wc = w & 3, q = lane >> 4, r16 = lane & 15;
    const int aB = (q * 256 + wr * 128 + r16) * 8;           // + m*128 ; +8192 lo
    const int bB = 16384 + (q * 256 + wc * 64 + r16) * 8;    // + n*128 ; +8192 lo

    f32x4 acc[8][4] = {};

    // prologue: stage tile 0 into buffer 0
    gload16(A1h + aG,      &sm[s0]);
    gload16(A1h + aG + 16, &sm[4096 + s0]);
    gload16(A1l + aG,      &sm[8192 + s0]);
    gload16(A1l + aG + 16, &sm[8192 + 4096 + s0]);
    gload16(xTh + bG,      &sm[16384 + s0]);
    gload16(xTh + bG + 16, &sm[16384 + 4096 + s0]);
    if (THIRD) {
        gload16(xTl + bG,      &sm[24576 + s0]);
        gload16(xTl + bG + 16, &sm[24576 + 4096 + s0]);
    }
    __syncthreads();

    for (int t = 0; t < 48; ++t) {
        const int cb = (t & 1) << 15;
        const int nb = cb ^ 32768;
        const size_t kn = (size_t)(t + 1) * 32;
        const bool pf = (t < 47);
        #pragma unroll
        for (int p = 0; p < 4; ++p) {
            const int mh = p >> 1, nh = p & 1;
            bf16x8 ah[4], al[4], bh[2], bl[2];
            #pragma unroll
            for (int i = 0; i < 4; ++i) {
                ah[i] = *(const bf16x8*)&sm[cb + aB + (mh * 4 + i) * 128];
                al[i] = *(const bf16x8*)&sm[cb + 8192 + aB + (mh * 4 + i) * 128];
            }
            #pragma unroll
            for (int nn = 0; nn < 2; ++nn) {
                bh[nn] = *(const bf16x8*)&sm[cb + bB + (nh * 2 + nn) * 128];
                if (THIRD)
                    bl[nn] = *(const bf16x8*)&sm[cb + 8192 + bB + (nh * 2 + nn) * 128];
            }
            if (p == 0 && pf) {   // prefetch next tile: A-half
                gload16(A1h + aG + kn,      &sm[nb + s0]);
                gload16(A1h + aG + kn + 16, &sm[nb + 4096 + s0]);
                gload16(A1l + aG + kn,      &sm[nb + 8192 + s0]);
                gload16(A1l + aG + kn + 16, &sm[nb + 8192 + 4096 + s0]);
            }
            if (p == 1 && pf) {   // prefetch next tile: B-half
                gload16(xTh + bG + kn,      &sm[nb + 16384 + s0]);
                gload16(xTh + bG + kn + 16, &sm[nb + 16384 + 4096 + s0]);
                if (THIRD) {
                    gload16(xTl + bG + kn,      &sm[nb + 24576 + s0]);
                    gload16(xTl + bG + kn + 16, &sm[nb + 24576 + 4096 + s0]);
                }
            }
            __builtin_amdgcn_s_barrier();
            __builtin_amdgcn_s_setprio(1);
            #pragma unroll
            for (int i = 0; i < 4; ++i)
                #pragma unroll
                for (int nn = 0; nn < 2; ++nn) {
                    const int mi = mh * 4 + i, ni = nh * 2 + nn;
                    acc[mi][ni] = __builtin_amdgcn_mfma_f32_16x16x32_bf16(ah[i], bh[nn], acc[mi][ni], 0, 0, 0);
                    acc[mi][ni] = __builtin_amdgcn_mfma_f32_16x16x32_bf16(al[i], bh[nn], acc[mi][ni], 0, 0, 0);
                    if (THIRD)
                        acc[mi][ni] = __builtin_amdgcn_mfma_f32_16x16x32_bf16(ah[i], bl[nn], acc[mi][ni], 0, 0, 0);
                }
            __builtin_amdgcn_s_setprio(0);
            __builtin_amdgcn_s_barrier();
        }
        __syncthreads();   // single vmcnt drain per K-step: next buffer ready
    }

    // bias + relu (in place)
    const float* bb = (o0 < HID_) ? (bc1 + o0) : (bs1 + (o0 - HID_));
    #pragma unroll
    for (int m = 0; m < 8; ++m)
        #pragma unroll
        for (int r = 0; r < 4; ++r) {
            const float bv = bb[wr * 128 + m * 16 + q * 4 + r];
            #pragma unroll
            for (int n = 0; n < 4; ++n)
                acc[m][n][r] = fmaxf(acc[m][n][r] + bv, 0.f);
        }

    // epilogue: 2 passes (hi/lo) x 2 j-halves via LDS transpose [128][264]
    const int jq = wc >> 1;          // wave's j-half
    const int jl0 = (wc & 1) * 64;   // j offset within half
    for (int pass = 0; pass < 2; ++pass)
        for (int jh = 0; jh < 2; ++jh) {
            __syncthreads();
            if (jq == jh) {
                #pragma unroll
                for (int m = 0; m < 8; ++m)
                    #pragma unroll
                    for (int n = 0; n < 4; ++n) {
                        u16 o4[4];
                        #pragma unroll
                        for (int r = 0; r < 4; ++r) {
                            const float v = acc[m][n][r];
                            const u16 hi = f2bf(v);
                            o4[r] = pass ? f2bf(v - bf2f(hi)) : hi;
                        }
                        *(uint2*)&sm[(jl0 + n * 16 + r16) * 264 + wr * 128 + m * 16 + q * 4] =
                            make_uint2((u32)o4[0] | ((u32)o4[1] << 16),
                                       (u32)o4[2] | ((u32)o4[3] << 16));
                    }
            }
            __syncthreads();
            const int jr = tid >> 2, ck = (tid & 3) * 64;
            u16* dst = (pass ? H1Tl : H1Th) +
                       ((size_t)b * N_ + j0 + jh * 128 + jr) * 1024 + o0 + ck;
            #pragma unroll
            for (int u = 0; u < 8; ++u)
                *(uint4*)(dst + u * 8) = *(const uint4*)&sm[jr * 264 + ck + u * 8];
        }
}

// ---------------------------------------------------------------- K2: conv2 via split-bf16 MFMA
// mt 0/1: f rows (Wc2, K-slice 0:512); mt 2: p rows (Ws2, K-slice 512:1024). BM=64, BN=128.
__global__ __launch_bounds__(256)
void k_conv2_mfma(const u16* __restrict__ A2h, const u16* __restrict__ A2l,
                  const u16* __restrict__ H1Th, const u16* __restrict__ H1Tl,
                  const float* __restrict__ bc2, const float* __restrict__ bs2,
                  float* __restrict__ ff, u16* __restrict__ fTh, float* __restrict__ pbuf)
{
    __shared__ u16 sm[12288];   // Ah 2K | Al 2K | Bh 4K | Bl 4K (u16)
    const int tid = threadIdx.x;
    const int j0 = blockIdx.x * 128, mt = blockIdx.y, b = blockIdx.z;
    const int koff = (mt == 2) ? HID_ : 0;

    const int rA = tid & 63, kbA = tid >> 6;
    const size_t aOff = (size_t)(mt * 64 + rA) * HID_ + kbA * 8;
    const int rB = tid & 127, kbB = tid >> 7;
    const size_t bOff  = ((size_t)b * N_ + j0 + rB) * 1024 + koff + kbB * 8;
    const size_t bOff1 = bOff + 16;

    const int w = tid >> 6, lane = tid & 63;
    const int wr = w >> 1, wc = w & 1, q = lane >> 4, r16 = lane & 15;

    f32x4 acc[2][4] = {};
    for (int k0 = 0; k0 < HID_; k0 += 32) {
        __syncthreads();
        gload16(A2h + aOff + k0, &sm[tid * 8]);
        gload16(A2l + aOff + k0, &sm[2048 + tid * 8]);
        gload16(H1Th + bOff + k0,  &sm[4096 + tid * 8]);
        gload16(H1Th + bOff1 + k0, &sm[4096 + (tid + 256) * 8]);
        gload16(H1Tl + bOff + k0,  &sm[8192 + tid * 8]);
        gload16(H1Tl + bOff1 + k0, &sm[8192 + (tid + 256) * 8]);
        __syncthreads();
        bf16x8 ah[2], al[2], bh[4], bl[4];
        #pragma unroll
        for (int m = 0; m < 2; ++m) {
            const int idx = (q * 64 + wr * 32 + m * 16 + r16) * 8;
            ah[m] = *(const bf16x8*)&sm[idx];
            al[m] = *(const bf16x8*)&sm[2048 + idx];
        }
        #pragma unroll
        for (int n = 0; n < 4; ++n) {
            const int idx = (q * 128 + wc * 64 + n * 16 + r16) * 8;
            bh[n] = *(const bf16x8*)&sm[4096 + idx];
            bl[n] = *(const bf16x8*)&sm[8192 + idx];
        }
        #pragma unroll
        for (int m = 0; m < 2; ++m)
            #pragma unroll
            for (int n = 0; n < 4; ++n) {
                acc[m][n] = __builtin_amdgcn_mfma_f32_16x16x32_bf16(ah[m], bh[n], acc[m][n], 0, 0, 0);
                acc[m][n] = __builtin_amdgcn_mfma_f32_16x16x32_bf16(al[m], bh[n], acc[m][n], 0, 0, 0);
                acc[m][n] = __builtin_amdgcn_mfma_f32_16x16x32_bf16(ah[m], bl[n], acc[m][n], 0, 0, 0);
            }
    }
    const float* bb = (mt == 0) ? bc2 : (mt == 1 ? bc2 + 64 : bs2);
    #pragma unroll
    for (int m = 0; m < 2; ++m) {
        const int lB = wr * 32 + m * 16 + q * 4;
        #pragma unroll
        for (int n = 0; n < 4; ++n) {
            const int jl = wc * 64 + n * 16 + r16;
            float v[4];
            #pragma unroll
            for (int r = 0; r < 4; ++r) v[r] = acc[m][n][r] + bb[lB + r];
            if (mt < 2) {
                #pragma unroll
                for (int r = 0; r < 4; ++r)
                    ff[((size_t)b * L_ + mt * 64 + lB + r) * N_ + j0 + jl] = v[r];
                *(uint2*)&fTh[((size_t)b * N_ + j0 + jl) * L_ + mt * 64 + lB] =
                    make_uint2((u32)f2bf(v[0]) | ((u32)f2bf(v[1]) << 16),
                               (u32)f2bf(v[2]) | ((u32)f2bf(v[3]) << 16));
            } else {
                #pragma unroll
                for (int r = 0; r < 4; ++r)
                    pbuf[((size_t)b * M_ + lB + r) * N_ + j0 + jl] = v[r];
            }
        }
    }
}

// ---------------------------------------------------------------- fn: row-normalize fT -> fnT (bf16)
__global__ __launch_bounds__(256)
void k_fn(const u16* __restrict__ fTh, u16* __restrict__ fnT)
{
    const int tid = threadIdx.x;
    const int row = blockIdx.x * 32 + (tid >> 3);
    const int l8 = tid & 7;
    const u16* src = fTh + (size_t)row * L_ + l8 * 16;
    const uint4 va = *(const uint4*)src;
    const uint4 vb = *(const uint4*)(src + 8);
    float f[16];
    f[0]=bflo(va.x); f[1]=bfhi(va.x); f[2]=bflo(va.y); f[3]=bfhi(va.y);
    f[4]=bflo(va.z); f[5]=bfhi(va.z); f[6]=bflo(va.w); f[7]=bfhi(va.w);
    f[8]=bflo(vb.x); f[9]=bfhi(vb.x); f[10]=bflo(vb.y); f[11]=bfhi(vb.y);
    f[12]=bflo(vb.z); f[13]=bfhi(vb.z); f[14]=bflo(vb.w); f[15]=bfhi(vb.w);
    float ss = 0.f;
    #pragma unroll
    for (int i = 0; i < 16; ++i) ss = fmaf(f[i], f[i], ss);
    ss += __shfl_xor(ss, 1); ss += __shfl_xor(ss, 2); ss += __shfl_xor(ss, 4);
    const float inv = 1.f / fmaxf(sqrtf(ss), 1e-12f);
    u32 p[8];
    #pragma unroll
    for (int i2 = 0; i2 < 8; ++i2)
        p[i2] = (u32)f2bf(f[i2*2] * inv) | ((u32)f2bf(f[i2*2+1] * inv) << 16);
    u16* dst = fnT + (size_t)row * L_ + l8 * 16;
    *(uint4*)(dst + 0) = make_uint4(p[0], p[1], p[2], p[3]);
    *(uint4*)(dst + 8) = make_uint4(p[4], p[5], p[6], p[7]);
}

__global__ __launch_bounds__(256)
void k_zero(float* __restrict__ p, int n)
{
    const int i = blockIdx.x * 256 + threadIdx.x;
    if (i < n) p[i] = 0.f;
}

// ---------------------------------------------------------------- burst: bw[b][j] += sum_k sigmoid(a*sim+b), sim via bf16 MFMA
__global__ __launch_bounds__(256)
void k_burst_mfma(const u16* __restrict__ fnT, const float* __restrict__ pa,
                  const float* __restrict__ pbv, float* __restrict__ bw)
{
    __shared__ u16 sm[8192];    // A 4K | B 4K
    const int tid = threadIdx.x;
    const int j0 = blockIdx.x * 128, k0t = blockIdx.y * 128, b = blockIdx.z;
    const float aa = *pa, bcst = *pbv;

    const int rB = tid & 127, kbB = tid >> 7;
    const size_t aOff  = ((size_t)b * N_ + j0 + rB) * L_ + kbB * 8;
    const size_t aOff1 = aOff + 16;
    const size_t bOff  = ((size_t)b * N_ + k0t + rB) * L_ + kbB * 8;
    const size_t bOff1 = bOff + 16;

    const int w = tid >> 6, lane = tid & 63;
    const int wr = w >> 1, wc = w & 1, q = lane >> 4, r16 = lane & 15;
    const int aBase = (q * 128 + wr * 64 + r16) * 8;
    const int bBase = (q * 128 + wc * 64 + r16) * 8;

    f32x4 acc[4][4] = {};
    for (int k0 = 0; k0 < L_; k0 += 32) {
        __syncthreads();
        gload16(fnT + aOff + k0,  &sm[tid * 8]);
        gload16(fnT + aOff1 + k0, &sm[(tid + 256) * 8]);
        gload16(fnT + bOff + k0,  &sm[4096 + tid * 8]);
        gload16(fnT + bOff1 + k0, &sm[4096 + (tid + 256) * 8]);
        __syncthreads();
        bf16x8 a[4], bv[4];
        #pragma unroll
        for (int m = 0; m < 4; ++m) a[m]  = *(const bf16x8*)&sm[aBase + m * 128];
        #pragma unroll
        for (int n = 0; n < 4; ++n) bv[n] = *(const bf16x8*)&sm[4096 + bBase + n * 128];
        #pragma unroll
        for (int m = 0; m < 4; ++m)
            #pragma unroll
            for (int n = 0; n < 4; ++n)
                acc[m][n] = __builtin_amdgcn_mfma_f32_16x16x32_bf16(a[m], bv[n], acc[m][n], 0, 0, 0);
    }
    #pragma unroll
    for (int m = 0; m < 4; ++m)
        #pragma unroll
        for (int r = 0; r < 4; ++r) {
            float s = 0.f;
            #pragma unroll
            for (int n = 0; n < 4; ++n)
                s += 1.f / (1.f + __expf(-(fmaf(aa, acc[m][n][r], bcst))));
            s += __shfl_xor(s, 1); s += __shfl_xor(s, 2);
            s += __shfl_xor(s, 4); s += __shfl_xor(s, 8);
            if (r16 == 0)
                atomicAdd(&bw[b * N_ + j0 + wr * 64 + m * 16 + q * 4 + r], s);
        }
}

// ---------------------------------------------------------------- token MLP
__global__ __launch_bounds__(256)
void k_tok1(const float* __restrict__ t, const float* __restrict__ W,
            const float* __restrict__ bias, float* __restrict__ outv)
{
    const int b = blockIdx.y;
    const int o = blockIdx.x * 8 + (threadIdx.x >> 5);
    const int lane = threadIdx.x & 31;
    const float* tb = t + (size_t)b * C_;
    const float* wv = W + (size_t)o * C_;
    float s = 0.f;
    for (int c = lane; c < C_; c += 32) s = fmaf(wv[c], tb[c], s);
    for (int off = 16; off; off >>= 1) s += __shfl_down(s, off, 32);
    if (lane == 0) outv[b * HID_ + o] = fmaxf(s + bias[o], 0.f);
}

__global__ __launch_bounds__(256)
void k_tok2(const float* __restrict__ h, const float* __restrict__ W,
            const float* __restrict__ bias, float* __restrict__ outv)
{
    const int b = blockIdx.y;
    const int o = blockIdx.x * 8 + (threadIdx.x >> 5);
    const int lane = threadIdx.x & 31;
    const float* hb = h + (size_t)b * HID_;
    const float* wv = W + (size_t)o * HID_;
    float s = 0.f;
    for (int c = lane; c < HID_; c += 32) s = fmaf(wv[c], hb[c], s);
    for (int off = 16; off; off >>= 1) s += __shfl_down(s, off, 32);
    if (lane == 0) outv[b * G_ + o] = s + bias[o];
}

// ---------------------------------------------------------------- Sinkhorn (3 iters, 1 block/batch)
__global__ __launch_bounds__(1024)
void k_sinkhorn(const float* __restrict__ pbuf, const float* __restrict__ dustp,
                float* __restrict__ Pbuf)
{
    const int b = blockIdx.x;
    const int tid = threadIdx.x;
    const float dust = *dustp;
    const float* Zb = pbuf + (size_t)b * M_ * N_;
    float* Pb = Pbuf + (size_t)b * M_ * N_;
    __shared__ float v_s[N_];
    __shared__ float u_s[M_ + 1];
    const float normc = -logf(1088.0f);
    const float lmu_dust = logf(1024.0f) + normc;

    v_s[tid] = 0.f;
    __syncthreads();
    const int wv = tid >> 6, lane = tid & 63;

    for (int it = 0; it < 3; ++it) {
        for (int i = wv; i < 65; i += 16) {
            float zz[16];
            #pragma unroll
            for (int qq = 0; qq < 16; ++qq) {
                const int j = lane + (qq << 6);
                const float z = (i < 64) ? Zb[(size_t)i * N_ + j] : dust;
                zz[qq] = z + v_s[j];
            }
            float mx = zz[0];
            #pragma unroll
            for (int qq = 1; qq < 16; ++qq) mx = fmaxf(mx, zz[qq]);
            #pragma unroll
            for (int off = 32; off; off >>= 1) mx = fmaxf(mx, __shfl_xor(mx, off));
            float s = 0.f;
            #pragma unroll
            for (int qq = 0; qq < 16; ++qq) s += __expf(zz[qq] - mx);
            #pragma unroll
            for (int off = 32; off; off >>= 1) s += __shfl_xor(s, off);
            if (lane == 0)
                u_s[i] = ((i < 64) ? normc : lmu_dust) - (mx + __logf(s));
        }
        __syncthreads();
        {
            float mx = -INFINITY, s = 0.f;
            for (int i = 0; i < 64; ++i) {
                const float z = Zb[(size_t)i * N_ + tid] + u_s[i];
                const float nm = fmaxf(mx, z);
                s = s * __expf(mx - nm) + __expf(z - nm);
                mx = nm;
            }
            { const float z = dust + u_s[64];
              const float nm = fmaxf(mx, z);
              s = s * __expf(mx - nm) + __expf(z - nm);
              mx = nm; }
            v_s[tid] = normc - (mx + __logf(s));
        }
        __syncthreads();
    }
    const float vvv = v_s[tid];
    for (int i = 0; i < 64; ++i)
        Pb[(size_t)i * N_ + tid] =
            __expf(Zb[(size_t)i * N_ + tid] + u_s[i] + vvv - normc);
}

// ---------------------------------------------------------------- agg[b][l][m] = sum_j f[l][j]*P[m][j]*bw[j]^-p
__global__ __launch_bounds__(256)
void k_agg(const float* __restrict__ fbuf, const float* __restrict__ Pbuf,
           const float* __restrict__ bw, const float* __restrict__ bp,
           float* __restrict__ agg)
{
    const int b = blockIdx.x;
    const int l0 = blockIdx.y * 32;
    const float pw = *bp;
    const float* fb = fbuf + ((size_t)b * L_ + l0) * N_;
    const float* Pb = Pbuf + (size_t)b * M_ * N_;
    const float* bwb = bw + b * N_;
    __shared__ float Fs[32][65];
    __shared__ float Ps[64][65];
    const int tid = threadIdx.x;
    const int tx = tid & 15, ty = tid >> 4;
    float acc[2][4];
    #pragma unroll
    for (int i = 0; i < 2; ++i)
        #pragma unroll
        for (int qq = 0; qq < 4; ++qq) acc[i][qq] = 0.f;

    for (int j0 = 0; j0 < N_; j0 += 64) {
        __syncthreads();
        for (int idx = tid; idx < 32 * 64; idx += 256) {
            const int li = idx >> 6, jj = idx & 63;
            Fs[li][jj] = fb[(size_t)li * N_ + j0 + jj];
        }
        for (int idx = tid; idx < 64 * 64; idx += 256) {
            const int mi = idx >> 6, jj = idx & 63;
            const float iwv = __expf(-pw * __logf(bwb[j0 + jj]));
            Ps[mi][jj] = Pb[(size_t)mi * N_ + j0 + jj] * iwv;
        }
        __syncthreads();
        for (int jj = 0; jj < 64; ++jj) {
            const float a0 = Fs[ty * 2 + 0][jj];
            const float a1 = Fs[ty * 2 + 1][jj];
            #pragma unroll
            for (int qq = 0; qq < 4; ++qq) {
                const float bq = Ps[tx * 4 + qq][jj];
                acc[0][qq] = fmaf(a0, bq, acc[0][qq]);
                acc[1][qq] = fmaf(a1, bq, acc[1][qq]);
            }
        }
    }
    #pragma unroll
    for (int i = 0; i < 2; ++i)
        #pragma unroll
        for (int qq = 0; qq < 4; ++qq)
            agg[((size_t)b * L_ + l0 + ty * 2 + i) * M_ + tx * 4 + qq] = acc[i][qq];
}

// ---------------------------------------------------------------- final norms + concat
__global__ __launch_bounds__(256)
void k_final(const float* __restrict__ tk, const float* __restrict__ agg,
             float* __restrict__ out)
{
    const int b = blockIdx.x;
    const int tid = threadIdx.x;
    const float* ab = agg + (size_t)b * L_ * M_;
    __shared__ float red[256];
    __shared__ float colred[4][64];
    __shared__ float sa[64];
    __shared__ float bcast[2];

    const float tv = tk[b * G_ + tid];
    red[tid] = tv * tv;
    __syncthreads();
    for (int s = 128; s > 0; s >>= 1) { if (tid < s) red[tid] += red[tid + s]; __syncthreads(); }
    if (tid == 0) bcast[0] = 1.f / fmaxf(sqrtf(red[0]), 1e-12f);
    __syncthreads();
    const float tkn = tv * bcast[0];

    const int mi = tid & 63, part = tid >> 6;
    float cs = 0.f;
    for (int li = part; li < L_; li += 4) { const float v = ab[li * M_ + mi]; cs = fmaf(v, v, cs); }
    colred[part][mi] = cs;
    __syncthreads();
    if (tid < 64)
        sa[tid] = 1.f / fmaxf(sqrtf(colred[0][tid] + colred[1][tid] +
                                    colred[2][tid] + colred[3][tid]), 1e-12f);
    __syncthreads();

    float tot = tkn * tkn;
    for (int idx = tid; idx < L_ * M_; idx += 256) {
        const float v = ab[idx] * sa[idx & 63];
        tot = fmaf(v, v, tot);
    }
    __syncthreads();
    red[tid] = tot;
    __syncthreads();
    for (int s = 128; s > 0; s >>= 1) { if (tid < s) red[tid] += red[tid + s]; __syncthreads(); }
    if (tid == 0) bcast[1] = 1.f / fmaxf(sqrtf(red[0]), 1e-12f);
    __syncthreads();
    const float invT = bcast[1];

    float* ob = out + (size_t)b * (G_ + L_ * M_);
    ob[tid] = tkn * invT;
    for (int idx = tid; idx < L_ * M_; idx += 256)
        ob[G_ + idx] = ab[idx] * sa[idx & 63] * invT;
}

// ----------------------------------------------------------------
extern "C" void kernel_launch(void* const* d_in, const int* in_sizes, int n_in,
                              void* d_out, int out_size, void* d_ws, size_t ws_size,
                              hipStream_t stream)
{
    const float* x    = (const float*)d_in[0];
    const float* t    = (const float*)d_in[1];
    const float* Wc1  = (const float*)d_in[2];
    const float* bc1  = (const float*)d_in[3];
    const float* Wc2  = (const float*)d_in[4];
    const float* bc2  = (const float*)d_in[5];
    const float* Ws1  = (const float*)d_in[6];
    const float* bs1  = (const float*)d_in[7];
    const float* Ws2  = (const float*)d_in[8];
    const float* bs2  = (const float*)d_in[9];
    const float* Wt1  = (const float*)d_in[10];
    const float* bt1  = (const float*)d_in[11];
    const float* Wt2  = (const float*)d_in[12];
    const float* bt2  = (const float*)d_in[13];
    const float* dust = (const float*)d_in[14];
    const float* ba   = (const float*)d_in[15];
    const float* bbv  = (const float*)d_in[16];
    const float* bp   = (const float*)d_in[17];

    char* ws = (char*)d_ws;
    // fixed region
    u16* A1h  = (u16*)(ws + 0);            // 1024x1536
    u16* A1l  = (u16*)(ws + 3145728);
    u16* A2h  = (u16*)(ws + 6291456);      // 192x512
    u16* A2l  = (u16*)(ws + 6488064);
    u16* H1Th = (u16*)(ws + 6684672);      // 32x1024x1024
    u16* H1Tl = (u16*)(ws + 73793536);
    float* tkb = (float*)(ws + 140902400);
    float* htb = (float*)(ws + 140935168);
    float* bw  = (float*)(ws + 141000704);
    // xT region (reused after conv1 for downstream buffers)
    const size_t base0 = 141131776;
    u16*   xTh  = (u16*)(ws + base0);
    float* pb   = (float*)(ws + base0);                // alias xTh: live after conv1
    float* Pb   = (float*)(ws + base0 + 8388608);
    u16*   fTh  = (u16*)(ws + base0 + 16777216);
    u16*   fnT  = (u16*)(ws + base0 + 25165824);
    float* ff   = (float*)(ws + base0 + 33554432);
    float* aggb = (float*)(ws + base0 + 50331648);
    const size_t NEED3 = base0 + 2ull * 100663296ull;  // with xTl
    u16* xTl = (u16*)(ws + base0 + 100663296);
    const bool third = (ws_size >= NEED3);
    if (!third) xTl = xTh;   // unused in 2-term path

    // --- prep: weight splits + x transpose/split
    k_split<<<768, 256, 0, stream>>>(Wc1, A1h, A1l, 512 * C_ / 4);
    k_split<<<768, 256, 0, stream>>>(Ws1, A1h + (size_t)512 * C_, A1l + (size_t)512 * C_, 512 * C_ / 4);
    k_split<<<64, 256, 0, stream>>>(Wc2, A2h, A2l, 128 * HID_ / 4);
    k_split<<<32, 256, 0, stream>>>(Ws2, A2h + (size_t)128 * HID_, A2l + (size_t)128 * HID_, 64 * HID_ / 4);
    if (third) k_prep_xt<1><<<dim3(16, 24, B_), 256, 0, stream>>>(x, xTh, xTl);
    else       k_prep_xt<0><<<dim3(16, 24, B_), 256, 0, stream>>>(x, xTh, xTl);

    // --- conv stacks (MFMA)
    if (third) k_conv1_v3<1><<<dim3(4, 4, B_), 512, 0, stream>>>(A1h, A1l, xTh, xTl, bc1, bs1, H1Th, H1Tl);
    else       k_conv1_v3<0><<<dim3(4, 4, B_), 512, 0, stream>>>(A1h, A1l, xTh, xTl, bc1, bs1, H1Th, H1Tl);
    k_conv2_mfma<<<dim3(8, 3, B_), 256, 0, stream>>>(A2h, A2l, H1Th, H1Tl, bc2, bs2, ff, fTh, pb);

    // --- token MLP
    k_tok1<<<dim3(64, B_), 256, 0, stream>>>(t, Wt1, bt1, htb);
    k_tok2<<<dim3(32, B_), 256, 0, stream>>>(htb, Wt2, bt2, tkb);

    // --- Sinkhorn
    k_sinkhorn<<<dim3(B_), 1024, 0, stream>>>(pb, dust, Pb);

    // --- burst reweighting
    k_fn<<<1024, 256, 0, stream>>>(fTh, fnT);
    k_zero<<<128, 256, 0, stream>>>(bw, B_ * N_);
    k_burst_mfma<<<dim3(8, 8, B_), 256, 0, stream>>>(fnT, ba, bbv, bw);

    // --- aggregation + final norms
    k_agg<<<dim3(B_, 4), 256, 0, stream>>>(ff, Pb, bw, bp, aggb);
    k_final<<<dim3(B_), 256, 0, stream>>>(tkb, aggb, (float*)d_out);
}

// Round 5
// 916.270 us; speedup vs baseline: 1.3806x; 1.3806x over previous
//
#include <hip/hip_runtime.h>
#include <math.h>

#define B_   32
#define C_   1536
#define N_   1024
#define HID_ 512
#define L_   128
#define M_   64
#define G_   256

typedef unsigned short u16;
typedef unsigned int   u32;
typedef short bf16x8 __attribute__((ext_vector_type(8)));
typedef float f32x4  __attribute__((ext_vector_type(4)));

__device__ __forceinline__ u16 f2bf(float v) {
    u32 u = __float_as_uint(v);
    return (u16)((u + 0x7fffu + ((u >> 16) & 1u)) >> 16);   // RNE
}
__device__ __forceinline__ float bf2f(u16 b) { return __uint_as_float(((u32)b) << 16); }
__device__ __forceinline__ float bflo(u32 u) { return __uint_as_float(u << 16); }
__device__ __forceinline__ float bfhi(u32 u) { return __uint_as_float(u & 0xffff0000u); }

__device__ __forceinline__ void gload16(const u16* g, u16* l) {
    __builtin_amdgcn_global_load_lds(
        (const __attribute__((address_space(1))) void*)g,
        (__attribute__((address_space(3))) void*)l, 16, 0, 0);
}

// ---------------------------------------------------------------- prep: split f32 -> bf16 hi/lo
__global__ __launch_bounds__(256)
void k_split(const float* __restrict__ src, u16* __restrict__ h, u16* __restrict__ l, int n4)
{
    const int i = blockIdx.x * 256 + threadIdx.x;
    if (i >= n4) return;
    const float4 v = ((const float4*)src)[i];
    const u16 h0 = f2bf(v.x), h1 = f2bf(v.y), h2 = f2bf(v.z), h3 = f2bf(v.w);
    *(uint2*)&h[(size_t)i * 4] =
        make_uint2((u32)h0 | ((u32)h1 << 16), (u32)h2 | ((u32)h3 << 16));
    const u16 l0 = f2bf(v.x - bf2f(h0)), l1 = f2bf(v.y - bf2f(h1));
    const u16 l2 = f2bf(v.z - bf2f(h2)), l3 = f2bf(v.w - bf2f(h3));
    *(uint2*)&l[(size_t)i * 4] =
        make_uint2((u32)l0 | ((u32)l1 << 16), (u32)l2 | ((u32)l3 << 16));
}

// ---------------------------------------------------------------- prep: transpose x [b][C][N] -> xT [b][N][C] bf16 (hi only)
__global__ __launch_bounds__(256)
void k_prep_xt(const float* __restrict__ x, u16* __restrict__ xTh)
{
    __shared__ float T[64][65];
    const int tid = threadIdx.x;
    const int j0 = blockIdx.x * 64, c0 = blockIdx.y * 64, b = blockIdx.z;
    const int row = tid >> 2, cq = (tid & 3) * 16;
    const float* src = x + ((size_t)b * C_ + c0 + row) * N_ + j0 + cq;
    *(float4*)&T[row][cq + 0]  = *(const float4*)(src + 0);
    *(float4*)&T[row][cq + 4]  = *(const float4*)(src + 4);
    *(float4*)&T[row][cq + 8]  = *(const float4*)(src + 8);
    *(float4*)&T[row][cq + 12] = *(const float4*)(src + 12);
    __syncthreads();
    u32 ph[8];
    #pragma unroll
    for (int i2 = 0; i2 < 8; ++i2) {
        const float f0 = T[cq + i2 * 2][row], f1 = T[cq + i2 * 2 + 1][row];
        ph[i2] = (u32)f2bf(f0) | ((u32)f2bf(f1) << 16);
    }
    u16* dh = xTh + ((size_t)b * N_ + j0 + row) * C_ + c0 + cq;
    *(uint4*)(dh + 0) = make_uint4(ph[0], ph[1], ph[2], ph[3]);
    *(uint4*)(dh + 8) = make_uint4(ph[4], ph[5], ph[6], ph[7]);
}

// ---------------------------------------------------------------- K1: conv1 via 2-term split-bf16 MFMA (proven 128x128 structure)
// H1T[b][j][o] (bf16 hi+lo) = relu(W[o]·x[b,:,j] + bias); W = Wh + Wl, x ~ xh.
__global__ __launch_bounds__(256)
void k_conv1_2t(const u16* __restrict__ A1h, const u16* __restrict__ A1l,
                const u16* __restrict__ xTh,
                const float* __restrict__ bc1, const float* __restrict__ bs1,
                u16* __restrict__ H1Th, u16* __restrict__ H1Tl)
{
    __shared__ u16 sm[17408];   // staging: Ah 4K | Al 4K | Bh 4K (u16); epilogue 128*136
    const int tid = threadIdx.x;
    const int j0 = blockIdx.x * 128, o0 = blockIdx.y * 128, b = blockIdx.z;

    const int r0 = tid & 127, kb0 = tid >> 7;
    const size_t aOff0 = (size_t)(o0 + r0) * C_ + kb0 * 8;
    const size_t aOff1 = aOff0 + 16;
    const size_t bOff0 = ((size_t)b * N_ + j0 + r0) * C_ + kb0 * 8;
    const size_t bOff1 = bOff0 + 16;

    const int w = tid >> 6, lane = tid & 63;
    const int wr = w >> 1, wc = w & 1, q = lane >> 4, r16 = lane & 15;
    const int aBase = (q * 128 + wr * 64 + r16) * 8;
    const int bBase = (q * 128 + wc * 64 + r16) * 8;

    f32x4 acc[4][4] = {};
    for (int k0 = 0; k0 < C_; k0 += 32) {
        __syncthreads();
        gload16(A1h + aOff0 + k0, &sm[tid * 8]);
        gload16(A1h + aOff1 + k0, &sm[(tid + 256) * 8]);
        gload16(A1l + aOff0 + k0, &sm[4096 + tid * 8]);
        gload16(A1l + aOff1 + k0, &sm[4096 + (tid + 256) * 8]);
        gload16(xTh + bOff0 + k0, &sm[8192 + tid * 8]);
        gload16(xTh + bOff1 + k0, &sm[8192 + (tid + 256) * 8]);
        __syncthreads();
        bf16x8 ah[4], al[4], bh[4];
        #pragma unroll
        for (int m = 0; m < 4; ++m) {
            ah[m] = *(const bf16x8*)&sm[aBase + m * 128];
            al[m] = *(const bf16x8*)&sm[4096 + aBase + m * 128];
        }
        #pragma unroll
        for (int n = 0; n < 4; ++n)
            bh[n] = *(const bf16x8*)&sm[8192 + bBase + n * 128];
        #pragma unroll
        for (int m = 0; m < 4; ++m)
            #pragma unroll
            for (int n = 0; n < 4; ++n) {
                acc[m][n] = __builtin_amdgcn_mfma_f32_16x16x32_bf16(ah[m], bh[n], acc[m][n], 0, 0, 0);
                acc[m][n] = __builtin_amdgcn_mfma_f32_16x16x32_bf16(al[m], bh[n], acc[m][n], 0, 0, 0);
            }
    }
    // epilogue: bias+relu, split hi/lo, LDS-transpose to H1T[j][o] (coalesced stores)
    const float* bb = (o0 < HID_) ? (bc1 + o0) : (bs1 + (o0 - HID_));
    const int oB = wr * 64 + q * 4;
    const int jB = wc * 64 + r16;
    #pragma unroll
    for (int pass = 0; pass < 2; ++pass) {
        __syncthreads();
        #pragma unroll
        for (int m = 0; m < 4; ++m)
            #pragma unroll
            for (int n = 0; n < 4; ++n) {
                u16 h4[4];
                #pragma unroll
                for (int r = 0; r < 4; ++r) {
                    const float v = fmaxf(acc[m][n][r] + bb[oB + m * 16 + r], 0.f);
                    const u16 hi = f2bf(v);
                    h4[r] = pass ? f2bf(v - bf2f(hi)) : hi;
                }
                *(uint2*)&sm[(jB + n * 16) * 136 + oB + m * 16] =
                    make_uint2((u32)h4[0] | ((u32)h4[1] << 16), (u32)h4[2] | ((u32)h4[3] << 16));
            }
        __syncthreads();
        u16* dst = pass ? H1Tl : H1Th;
        #pragma unroll
        for (int p = 0; p < 8; ++p) {
            const int j = p * 16 + (tid >> 4);
            const int col = (tid & 15) * 8;
            *(uint4*)&dst[((size_t)b * N_ + j0 + j) * 1024 + o0 + col] =
                *(const uint4*)&sm[j * 136 + col];
        }
    }
}

// ---------------------------------------------------------------- K2: conv2 via split-bf16 MFMA (3-term, proven)
// mt 0/1: f rows (Wc2, K-slice 0:512); mt 2: p rows (Ws2, K-slice 512:1024). BM=64, BN=128.
__global__ __launch_bounds__(256)
void k_conv2_mfma(const u16* __restrict__ A2h, const u16* __restrict__ A2l,
                  const u16* __restrict__ H1Th, const u16* __restrict__ H1Tl,
                  const float* __restrict__ bc2, const float* __restrict__ bs2,
                  float* __restrict__ ff, u16* __restrict__ fTh, float* __restrict__ pbuf)
{
    __shared__ u16 sm[12288];   // Ah 2K | Al 2K | Bh 4K | Bl 4K (u16)
    const int tid = threadIdx.x;
    const int j0 = blockIdx.x * 128, mt = blockIdx.y, b = blockIdx.z;
    const int koff = (mt == 2) ? HID_ : 0;

    const int rA = tid & 63, kbA = tid >> 6;
    const size_t aOff = (size_t)(mt * 64 + rA) * HID_ + kbA * 8;
    const int rB = tid & 127, kbB = tid >> 7;
    const size_t bOff  = ((size_t)b * N_ + j0 + rB) * 1024 + koff + kbB * 8;
    const size_t bOff1 = bOff + 16;

    const int w = tid >> 6, lane = tid & 63;
    const int wr = w >> 1, wc = w & 1, q = lane >> 4, r16 = lane & 15;

    f32x4 acc[2][4] = {};
    for (int k0 = 0; k0 < HID_; k0 += 32) {
        __syncthreads();
        gload16(A2h + aOff + k0, &sm[tid * 8]);
        gload16(A2l + aOff + k0, &sm[2048 + tid * 8]);
        gload16(H1Th + bOff + k0,  &sm[4096 + tid * 8]);
        gload16(H1Th + bOff1 + k0, &sm[4096 + (tid + 256) * 8]);
        gload16(H1Tl + bOff + k0,  &sm[8192 + tid * 8]);
        gload16(H1Tl + bOff1 + k0, &sm[8192 + (tid + 256) * 8]);
        __syncthreads();
        bf16x8 ah[2], al[2], bh[4], bl[4];
        #pragma unroll
        for (int m = 0; m < 2; ++m) {
            const int idx = (q * 64 + wr * 32 + m * 16 + r16) * 8;
            ah[m] = *(const bf16x8*)&sm[idx];
            al[m] = *(const bf16x8*)&sm[2048 + idx];
        }
        #pragma unroll
        for (int n = 0; n < 4; ++n) {
            const int idx = (q * 128 + wc * 64 + n * 16 + r16) * 8;
            bh[n] = *(const bf16x8*)&sm[4096 + idx];
            bl[n] = *(const bf16x8*)&sm[8192 + idx];
        }
        #pragma unroll
        for (int m = 0; m < 2; ++m)
            #pragma unroll
            for (int n = 0; n < 4; ++n) {
                acc[m][n] = __builtin_amdgcn_mfma_f32_16x16x32_bf16(ah[m], bh[n], acc[m][n], 0, 0, 0);
                acc[m][n] = __builtin_amdgcn_mfma_f32_16x16x32_bf16(al[m], bh[n], acc[m][n], 0, 0, 0);
                acc[m][n] = __builtin_amdgcn_mfma_f32_16x16x32_bf16(ah[m], bl[n], acc[m][n], 0, 0, 0);
            }
    }
    const float* bb = (mt == 0) ? bc2 : (mt == 1 ? bc2 + 64 : bs2);
    #pragma unroll
    for (int m = 0; m < 2; ++m) {
        const int lB = wr * 32 + m * 16 + q * 4;
        #pragma unroll
        for (int n = 0; n < 4; ++n) {
            const int jl = wc * 64 + n * 16 + r16;
            float v[4];
            #pragma unroll
            for (int r = 0; r < 4; ++r) v[r] = acc[m][n][r] + bb[lB + r];
            if (mt < 2) {
                #pragma unroll
                for (int r = 0; r < 4; ++r)
                    ff[((size_t)b * L_ + mt * 64 + lB + r) * N_ + j0 + jl] = v[r];
                *(uint2*)&fTh[((size_t)b * N_ + j0 + jl) * L_ + mt * 64 + lB] =
                    make_uint2((u32)f2bf(v[0]) | ((u32)f2bf(v[1]) << 16),
                               (u32)f2bf(v[2]) | ((u32)f2bf(v[3]) << 16));
            } else {
                #pragma unroll
                for (int r = 0; r < 4; ++r)
                    pbuf[((size_t)b * M_ + lB + r) * N_ + j0 + jl] = v[r];
            }
        }
    }
}

// ---------------------------------------------------------------- fn: row-normalize fT -> fnT (bf16)
__global__ __launch_bounds__(256)
void k_fn(const u16* __restrict__ fTh, u16* __restrict__ fnT)
{
    const int tid = threadIdx.x;
    const int row = blockIdx.x * 32 + (tid >> 3);
    const int l8 = tid & 7;
    const u16* src = fTh + (size_t)row * L_ + l8 * 16;
    const uint4 va = *(const uint4*)src;
    const uint4 vb = *(const uint4*)(src + 8);
    float f[16];
    f[0]=bflo(va.x); f[1]=bfhi(va.x); f[2]=bflo(va.y); f[3]=bfhi(va.y);
    f[4]=bflo(va.z); f[5]=bfhi(va.z); f[6]=bflo(va.w); f[7]=bfhi(va.w);
    f[8]=bflo(vb.x); f[9]=bfhi(vb.x); f[10]=bflo(vb.y); f[11]=bfhi(vb.y);
    f[12]=bflo(vb.z); f[13]=bfhi(vb.z); f[14]=bflo(vb.w); f[15]=bfhi(vb.w);
    float ss = 0.f;
    #pragma unroll
    for (int i = 0; i < 16; ++i) ss = fmaf(f[i], f[i], ss);
    ss += __shfl_xor(ss, 1); ss += __shfl_xor(ss, 2); ss += __shfl_xor(ss, 4);
    const float inv = 1.f / fmaxf(sqrtf(ss), 1e-12f);
    u32 p[8];
    #pragma unroll
    for (int i2 = 0; i2 < 8; ++i2)
        p[i2] = (u32)f2bf(f[i2*2] * inv) | ((u32)f2bf(f[i2*2+1] * inv) << 16);
    u16* dst = fnT + (size_t)row * L_ + l8 * 16;
    *(uint4*)(dst + 0) = make_uint4(p[0], p[1], p[2], p[3]);
    *(uint4*)(dst + 8) = make_uint4(p[4], p[5], p[6], p[7]);
}

__global__ __launch_bounds__(256)
void k_zero(float* __restrict__ p, int n)
{
    const int i = blockIdx.x * 256 + threadIdx.x;
    if (i < n) p[i] = 0.f;
}

// ---------------------------------------------------------------- burst: bw[b][j] += sum_k sigmoid(a*sim+b), sim via bf16 MFMA
__global__ __launch_bounds__(256)
void k_burst_mfma(const u16* __restrict__ fnT, const float* __restrict__ pa,
                  const float* __restrict__ pbv, float* __restrict__ bw)
{
    __shared__ u16 sm[8192];    // A 4K | B 4K
    const int tid = threadIdx.x;
    const int j0 = blockIdx.x * 128, k0t = blockIdx.y * 128, b = blockIdx.z;
    const float aa = *pa, bcst = *pbv;

    const int rB = tid & 127, kbB = tid >> 7;
    const size_t aOff  = ((size_t)b * N_ + j0 + rB) * L_ + kbB * 8;
    const size_t aOff1 = aOff + 16;
    const size_t bOff  = ((size_t)b * N_ + k0t + rB) * L_ + kbB * 8;
    const size_t bOff1 = bOff + 16;

    const int w = tid >> 6, lane = tid & 63;
    const int wr = w >> 1, wc = w & 1, q = lane >> 4, r16 = lane & 15;
    const int aBase = (q * 128 + wr * 64 + r16) * 8;
    const int bBase = (q * 128 + wc * 64 + r16) * 8;

    f32x4 acc[4][4] = {};
    for (int k0 = 0; k0 < L_; k0 += 32) {
        __syncthreads();
        gload16(fnT + aOff + k0,  &sm[tid * 8]);
        gload16(fnT + aOff1 + k0, &sm[(tid + 256) * 8]);
        gload16(fnT + bOff + k0,  &sm[4096 + tid * 8]);
        gload16(fnT + bOff1 + k0, &sm[4096 + (tid + 256) * 8]);
        __syncthreads();
        bf16x8 a[4], bv[4];
        #pragma unroll
        for (int m = 0; m < 4; ++m) a[m]  = *(const bf16x8*)&sm[aBase + m * 128];
        #pragma unroll
        for (int n = 0; n < 4; ++n) bv[n] = *(const bf16x8*)&sm[4096 + bBase + n * 128];
        #pragma unroll
        for (int m = 0; m < 4; ++m)
            #pragma unroll
            for (int n = 0; n < 4; ++n)
                acc[m][n] = __builtin_amdgcn_mfma_f32_16x16x32_bf16(a[m], bv[n], acc[m][n], 0, 0, 0);
    }
    #pragma unroll
    for (int m = 0; m < 4; ++m)
        #pragma unroll
        for (int r = 0; r < 4; ++r) {
            float s = 0.f;
            #pragma unroll
            for (int n = 0; n < 4; ++n)
                s += 1.f / (1.f + __expf(-(fmaf(aa, acc[m][n][r], bcst))));
            s += __shfl_xor(s, 1); s += __shfl_xor(s, 2);
            s += __shfl_xor(s, 4); s += __shfl_xor(s, 8);
            if (r16 == 0)
                atomicAdd(&bw[b * N_ + j0 + wr * 64 + m * 16 + q * 4 + r], s);
        }
}

// ---------------------------------------------------------------- token MLP
__global__ __launch_bounds__(256)
void k_tok1(const float* __restrict__ t, const float* __restrict__ W,
            const float* __restrict__ bias, float* __restrict__ outv)
{
    const int b = blockIdx.y;
    const int o = blockIdx.x * 8 + (threadIdx.x >> 5);
    const int lane = threadIdx.x & 31;
    const float* tb = t + (size_t)b * C_;
    const float* wv = W + (size_t)o * C_;
    float s = 0.f;
    for (int c = lane; c < C_; c += 32) s = fmaf(wv[c], tb[c], s);
    for (int off = 16; off; off >>= 1) s += __shfl_down(s, off, 32);
    if (lane == 0) outv[b * HID_ + o] = fmaxf(s + bias[o], 0.f);
}

__global__ __launch_bounds__(256)
void k_tok2(const float* __restrict__ h, const float* __restrict__ W,
            const float* __restrict__ bias, float* __restrict__ outv)
{
    const int b = blockIdx.y;
    const int o = blockIdx.x * 8 + (threadIdx.x >> 5);
    const int lane = threadIdx.x & 31;
    const float* hb = h + (size_t)b * HID_;
    const float* wv = W + (size_t)o * HID_;
    float s = 0.f;
    for (int c = lane; c < HID_; c += 32) s = fmaf(wv[c], hb[c], s);
    for (int off = 16; off; off >>= 1) s += __shfl_down(s, off, 32);
    if (lane == 0) outv[b * G_ + o] = s + bias[o];
}

// ---------------------------------------------------------------- Sinkhorn (3 iters, 1 block/batch)
__global__ __launch_bounds__(1024)
void k_sinkhorn(const float* __restrict__ pbuf, const float* __restrict__ dustp,
                float* __restrict__ Pbuf)
{
    const int b = blockIdx.x;
    const int tid = threadIdx.x;
    const float dust = *dustp;
    const float* Zb = pbuf + (size_t)b * M_ * N_;
    float* Pb = Pbuf + (size_t)b * M_ * N_;
    __shared__ float v_s[N_];
    __shared__ float u_s[M_ + 1];
    const float normc = -logf(1088.0f);
    const float lmu_dust = logf(1024.0f) + normc;

    v_s[tid] = 0.f;
    __syncthreads();
    const int wv = tid >> 6, lane = tid & 63;

    for (int it = 0; it < 3; ++it) {
        for (int i = wv; i < 65; i += 16) {
            float zz[16];
            #pragma unroll
            for (int qq = 0; qq < 16; ++qq) {
                const int j = lane + (qq << 6);
                const float z = (i < 64) ? Zb[(size_t)i * N_ + j] : dust;
                zz[qq] = z + v_s[j];
            }
            float mx = zz[0];
            #pragma unroll
            for (int qq = 1; qq < 16; ++qq) mx = fmaxf(mx, zz[qq]);
            #pragma unroll
            for (int off = 32; off; off >>= 1) mx = fmaxf(mx, __shfl_xor(mx, off));
            float s = 0.f;
            #pragma unroll
            for (int qq = 0; qq < 16; ++qq) s += __expf(zz[qq] - mx);
            #pragma unroll
            for (int off = 32; off; off >>= 1) s += __shfl_xor(s, off);
            if (lane == 0)
                u_s[i] = ((i < 64) ? normc : lmu_dust) - (mx + __logf(s));
        }
        __syncthreads();
        {
            float mx = -INFINITY, s = 0.f;
            for (int i = 0; i < 64; ++i) {
                const float z = Zb[(size_t)i * N_ + tid] + u_s[i];
                const float nm = fmaxf(mx, z);
                s = s * __expf(mx - nm) + __expf(z - nm);
                mx = nm;
            }
            { const float z = dust + u_s[64];
              const float nm = fmaxf(mx, z);
              s = s * __expf(mx - nm) + __expf(z - nm);
              mx = nm; }
            v_s[tid] = normc - (mx + __logf(s));
        }
        __syncthreads();
    }
    const float vvv = v_s[tid];
    for (int i = 0; i < 64; ++i)
        Pb[(size_t)i * N_ + tid] =
            __expf(Zb[(size_t)i * N_ + tid] + u_s[i] + vvv - normc);
}

// ---------------------------------------------------------------- agg[b][l][m] = sum_j f[l][j]*P[m][j]*bw[j]^-p
__global__ __launch_bounds__(256)
void k_agg(const float* __restrict__ fbuf, const float* __restrict__ Pbuf,
           const float* __restrict__ bw, const float* __restrict__ bp,
           float* __restrict__ agg)
{
    const int b = blockIdx.x;
    const int l0 = blockIdx.y * 32;
    const float pw = *bp;
    const float* fb = fbuf + ((size_t)b * L_ + l0) * N_;
    const float* Pb = Pbuf + (size_t)b * M_ * N_;
    const float* bwb = bw + b * N_;
    __shared__ float Fs[32][65];
    __shared__ float Ps[64][65];
    const int tid = threadIdx.x;
    const int tx = tid & 15, ty = tid >> 4;
    float acc[2][4];
    #pragma unroll
    for (int i = 0; i < 2; ++i)
        #pragma unroll
        for (int qq = 0; qq < 4; ++qq) acc[i][qq] = 0.f;

    for (int j0 = 0; j0 < N_; j0 += 64) {
        __syncthreads();
        for (int idx = tid; idx < 32 * 64; idx += 256) {
            const int li = idx >> 6, jj = idx & 63;
            Fs[li][jj] = fb[(size_t)li * N_ + j0 + jj];
        }
        for (int idx = tid; idx < 64 * 64; idx += 256) {
            const int mi = idx >> 6, jj = idx & 63;
            const float iwv = __expf(-pw * __logf(bwb[j0 + jj]));
            Ps[mi][jj] = Pb[(size_t)mi * N_ + j0 + jj] * iwv;
        }
        __syncthreads();
        for (int jj = 0; jj < 64; ++jj) {
            const float a0 = Fs[ty * 2 + 0][jj];
            const float a1 = Fs[ty * 2 + 1][jj];
            #pragma unroll
            for (int qq = 0; qq < 4; ++qq) {
                const float bq = Ps[tx * 4 + qq][jj];
                acc[0][qq] = fmaf(a0, bq, acc[0][qq]);
                acc[1][qq] = fmaf(a1, bq, acc[1][qq]);
            }
        }
    }
    #pragma unroll
    for (int i = 0; i < 2; ++i)
        #pragma unroll
        for (int qq = 0; qq < 4; ++qq)
            agg[((size_t)b * L_ + l0 + ty * 2 + i) * M_ + tx * 4 + qq] = acc[i][qq];
}

// ---------------------------------------------------------------- final norms + concat
__global__ __launch_bounds__(256)
void k_final(const float* __restrict__ tk, const float* __restrict__ agg,
             float* __restrict__ out)
{
    const int b = blockIdx.x;
    const int tid = threadIdx.x;
    const float* ab = agg + (size_t)b * L_ * M_;
    __shared__ float red[256];
    __shared__ float colred[4][64];
    __shared__ float sa[64];
    __shared__ float bcast[2];

    const float tv = tk[b * G_ + tid];
    red[tid] = tv * tv;
    __syncthreads();
    for (int s = 128; s > 0; s >>= 1) { if (tid < s) red[tid] += red[tid + s]; __syncthreads(); }
    if (tid == 0) bcast[0] = 1.f / fmaxf(sqrtf(red[0]), 1e-12f);
    __syncthreads();
    const float tkn = tv * bcast[0];

    const int mi = tid & 63, part = tid >> 6;
    float cs = 0.f;
    for (int li = part; li < L_; li += 4) { const float v = ab[li * M_ + mi]; cs = fmaf(v, v, cs); }
    colred[part][mi] = cs;
    __syncthreads();
    if (tid < 64)
        sa[tid] = 1.f / fmaxf(sqrtf(colred[0][tid] + colred[1][tid] +
                                    colred[2][tid] + colred[3][tid]), 1e-12f);
    __syncthreads();

    float tot = tkn * tkn;
    for (int idx = tid; idx < L_ * M_; idx += 256) {
        const float v = ab[idx] * sa[idx & 63];
        tot = fmaf(v, v, tot);
    }
    __syncthreads();
    red[tid] = tot;
    __syncthreads();
    for (int s = 128; s > 0; s >>= 1) { if (tid < s) red[tid] += red[tid + s]; __syncthreads(); }
    if (tid == 0) bcast[1] = 1.f / fmaxf(sqrtf(red[0]), 1e-12f);
    __syncthreads();
    const float invT = bcast[1];

    float* ob = out + (size_t)b * (G_ + L_ * M_);
    ob[tid] = tkn * invT;
    for (int idx = tid; idx < L_ * M_; idx += 256)
        ob[G_ + idx] = ab[idx] * sa[idx & 63] * invT;
}

// ----------------------------------------------------------------
extern "C" void kernel_launch(void* const* d_in, const int* in_sizes, int n_in,
                              void* d_out, int out_size, void* d_ws, size_t ws_size,
                              hipStream_t stream)
{
    const float* x    = (const float*)d_in[0];
    const float* t    = (const float*)d_in[1];
    const float* Wc1  = (const float*)d_in[2];
    const float* bc1  = (const float*)d_in[3];
    const float* Wc2  = (const float*)d_in[4];
    const float* bc2  = (const float*)d_in[5];
    const float* Ws1  = (const float*)d_in[6];
    const float* bs1  = (const float*)d_in[7];
    const float* Ws2  = (const float*)d_in[8];
    const float* bs2  = (const float*)d_in[9];
    const float* Wt1  = (const float*)d_in[10];
    const float* bt1  = (const float*)d_in[11];
    const float* Wt2  = (const float*)d_in[12];
    const float* bt2  = (const float*)d_in[13];
    const float* dust = (const float*)d_in[14];
    const float* ba   = (const float*)d_in[15];
    const float* bbv  = (const float*)d_in[16];
    const float* bp   = (const float*)d_in[17];

    char* ws = (char*)d_ws;
    // fixed region
    u16* A1h  = (u16*)(ws + 0);            // 1024x1536
    u16* A1l  = (u16*)(ws + 3145728);
    u16* A2h  = (u16*)(ws + 6291456);      // 192x512
    u16* A2l  = (u16*)(ws + 6488064);
    u16* H1Th = (u16*)(ws + 6684672);      // 32x1024x1024
    u16* H1Tl = (u16*)(ws + 73793536);
    float* tkb = (float*)(ws + 140902400);
    float* htb = (float*)(ws + 140935168);
    float* bw  = (float*)(ws + 141000704);
    // xT region (reused after conv1 for downstream buffers)
    const size_t base0 = 141131776;
    u16*   xTh  = (u16*)(ws + base0);
    float* pb   = (float*)(ws + base0);                // alias xTh: live after conv1
    float* Pb   = (float*)(ws + base0 + 8388608);
    u16*   fTh  = (u16*)(ws + base0 + 16777216);
    u16*   fnT  = (u16*)(ws + base0 + 25165824);
    float* ff   = (float*)(ws + base0 + 33554432);
    float* aggb = (float*)(ws + base0 + 50331648);

    // --- prep: weight splits + x transpose (bf16 hi only)
    k_split<<<768, 256, 0, stream>>>(Wc1, A1h, A1l, 512 * C_ / 4);
    k_split<<<768, 256, 0, stream>>>(Ws1, A1h + (size_t)512 * C_, A1l + (size_t)512 * C_, 512 * C_ / 4);
    k_split<<<64, 256, 0, stream>>>(Wc2, A2h, A2l, 128 * HID_ / 4);
    k_split<<<32, 256, 0, stream>>>(Ws2, A2h + (size_t)128 * HID_, A2l + (size_t)128 * HID_, 64 * HID_ / 4);
    k_prep_xt<<<dim3(16, 24, B_), 256, 0, stream>>>(x, xTh);

    // --- conv stacks (MFMA)
    k_conv1_2t<<<dim3(8, 8, B_), 256, 0, stream>>>(A1h, A1l, xTh, bc1, bs1, H1Th, H1Tl);
    k_conv2_mfma<<<dim3(8, 3, B_), 256, 0, stream>>>(A2h, A2l, H1Th, H1Tl, bc2, bs2, ff, fTh, pb);

    // --- token MLP
    k_tok1<<<dim3(64, B_), 256, 0, stream>>>(t, Wt1, bt1, htb);
    k_tok2<<<dim3(32, B_), 256, 0, stream>>>(htb, Wt2, bt2, tkb);

    // --- Sinkhorn
    k_sinkhorn<<<dim3(B_), 1024, 0, stream>>>(pb, dust, Pb);

    // --- burst reweighting
    k_fn<<<1024, 256, 0, stream>>>(fTh, fnT);
    k_zero<<<128, 256, 0, stream>>>(bw, B_ * N_);
    k_burst_mfma<<<dim3(8, 8, B_), 256, 0, stream>>>(fnT, ba, bbv, bw);

    // --- aggregation + final norms
    k_agg<<<dim3(B_, 4), 256, 0, stream>>>(ff, Pb, bw, bp, aggb);
    k_final<<<dim3(B_), 256, 0, stream>>>(tkb, aggb, (float*)d_out);
}